// Round 4
// baseline (285.982 us; speedup 1.0000x reference)
//
#include <hip/hip_runtime.h>

// DCTFreqConv, all-MFMA per-wave pipeline. Per sample (8x8 spatial block x 64ch):
//   GEMM1: Ct[t][c]  = sum_s  Xbf[c][s] * T[t][s]      (T = D (x) D, 64x64 bf16)
//   CONV : Y[o][t]   = sum_iw Wt[w][o][i]*Ct[t+w][i] + bias[o]   (3 shifted GEMMs)
//   GEMM3: out[s][c] = sum_t  U[s][t] * Y[t][c=o]      (U = T^T)
// Wave = 1 sample; 4 samples/WG; NO barriers (wave-local LDS regions).
// LDS: Ct[4][66][72] bf16 = 38016 B -> 4 WG/CU. d_ws: T | U | Wt bf16 (40960 B).

#define THREADS 256
#define HW 256
#define CH 64
#define CT_ROW 72                    // shorts per row (144 B, 16B-aligned)
#define CT_SAMPLE (66 * CT_ROW)      // rows 64,65 zero pad for conv t+2 shift
#define LDS_BYTES (4 * CT_SAMPLE * 2)

typedef __attribute__((ext_vector_type(8))) short short8b;
typedef __attribute__((ext_vector_type(8))) unsigned short us8;
typedef __attribute__((ext_vector_type(4))) float f32x4;
typedef __attribute__((ext_vector_type(4))) unsigned short us4;

__device__ inline unsigned short f2bf(float f) {
    unsigned u = __builtin_bit_cast(unsigned, f);
    u += 0x7FFFu + ((u >> 16) & 1u);
    return (unsigned short)(u >> 16);
}

__device__ __constant__ static const float D8[8][8] = {
  { 0.3535533906f, 0.3535533906f, 0.3535533906f, 0.3535533906f, 0.3535533906f, 0.3535533906f, 0.3535533906f, 0.3535533906f },
  { 0.4903926402f, 0.4157348062f, 0.2777851165f, 0.0975451610f,-0.0975451610f,-0.2777851165f,-0.4157348062f,-0.4903926402f },
  { 0.4619397663f, 0.1913417162f,-0.1913417162f,-0.4619397663f,-0.4619397663f,-0.1913417162f, 0.1913417162f, 0.4619397663f },
  { 0.4157348062f,-0.0975451610f,-0.4903926402f,-0.2777851165f, 0.2777851165f, 0.4903926402f, 0.0975451610f,-0.4157348062f },
  { 0.3535533906f,-0.3535533906f,-0.3535533906f, 0.3535533906f, 0.3535533906f,-0.3535533906f,-0.3535533906f, 0.3535533906f },
  { 0.2777851165f,-0.4903926402f, 0.0975451610f, 0.4157348062f,-0.4157348062f,-0.0975451610f, 0.4903926402f,-0.2777851165f },
  { 0.1913417162f,-0.4619397663f, 0.4619397663f,-0.1913417162f,-0.1913417162f, 0.4619397663f,-0.4619397663f, 0.1913417162f },
  { 0.0975451610f,-0.2777851165f, 0.4157348062f,-0.4903926402f, 0.4903926402f,-0.4157348062f, 0.2777851165f,-0.0975451610f },
};

// d_ws layout (shorts): [0,4096) Trm[t][s]; [4096,8192) Urm[s][t]; [8192,20480) Wt[w][o][i]
__global__ __launch_bounds__(256)
void prep_kernel(const float* __restrict__ conv_w, unsigned short* __restrict__ ws16) {
    int j = blockIdx.x * 256 + threadIdx.x;
    if (j < 4096) {
        int t = j >> 6, s = j & 63;
        ws16[j] = f2bf(D8[t >> 3][s >> 3] * D8[t & 7][s & 7]);
    } else if (j < 8192) {
        int jj = j - 4096;
        int s = jj >> 6, t = jj & 63;
        ws16[j] = f2bf(D8[t >> 3][s >> 3] * D8[t & 7][s & 7]);
    } else if (j < 20480) {
        int jj = j - 8192;
        int w = jj >> 12, rem = jj & 4095, o = rem >> 6, i = rem & 63;
        ws16[j] = f2bf(conv_w[o * 192 + i * 3 + w]);
    }
}

__global__ __launch_bounds__(THREADS, 4)
void dct_freq_conv_kernel(const float* __restrict__ x,
                          const unsigned short* __restrict__ ws16,
                          const float* __restrict__ conv_b,
                          float* __restrict__ out)
{
    extern __shared__ char smem[];
    unsigned short* Ct = (unsigned short*)smem;
    const unsigned short* Trm = ws16;
    const unsigned short* Urm = ws16 + 4096;
    const unsigned short* Wt  = ws16 + 8192;

    const int tid  = threadIdx.x;
    const int wid  = tid >> 6;
    const int lane = tid & 63;
    const int lr   = lane & 15;
    const int lq   = lane >> 4;
    const int bz   = blockIdx.z;
    const int by   = blockIdx.y;
    const int bxs  = blockIdx.x * 4 + wid;   // this wave's x-block

    unsigned short* CtP = Ct + wid * CT_SAMPLE;

    // zero pad rows t=64,65 (wave-local; compiler orders via lgkmcnt)
    if (lane < 36) *(us4*)&CtP[64 * CT_ROW + lane * 4] = (us4){0, 0, 0, 0};

    // bias per o-tile (hoisted; overlaps with GEMM1 latency)
    float bias[4];
    #pragma unroll
    for (int m = 0; m < 4; ++m) bias[m] = conv_b[m * 16 + lr];

    // ---- GEMM1: Ct[t][c] = sum_s Xbf[c][s]*T[t][s], split into c-halves ----
    #pragma unroll
    for (int mg = 0; mg < 2; ++mg) {
        f32x4 acc[2][4];
        #pragma unroll
        for (int i = 0; i < 2; ++i)
            #pragma unroll
            for (int n = 0; n < 4; ++n) acc[i][n] = (f32x4){0.f, 0.f, 0.f, 0.f};

        #pragma unroll
        for (int kc = 0; kc < 2; ++kc) {
            short8b a[2], b[4];
            #pragma unroll
            for (int mh = 0; mh < 2; ++mh) {
                const int c = (mg * 2 + mh) * 16 + lr;
                const float* xp = x + (((size_t)bz * CH + c) * HW + by * 8 + kc * 4 + lq) * HW
                                    + bxs * 8;
                float4 u0 = *(const float4*)xp;
                float4 u1 = *(const float4*)(xp + 4);
                us8 pa;
                pa[0] = f2bf(u0.x); pa[1] = f2bf(u0.y); pa[2] = f2bf(u0.z); pa[3] = f2bf(u0.w);
                pa[4] = f2bf(u1.x); pa[5] = f2bf(u1.y); pa[6] = f2bf(u1.z); pa[7] = f2bf(u1.w);
                a[mh] = __builtin_bit_cast(short8b, pa);
            }
            #pragma unroll
            for (int n = 0; n < 4; ++n)
                b[n] = *(const short8b*)&Trm[(n * 16 + lr) * 64 + kc * 32 + lq * 8];
            #pragma unroll
            for (int mh = 0; mh < 2; ++mh)
                #pragma unroll
                for (int n = 0; n < 4; ++n)
                    acc[mh][n] = __builtin_amdgcn_mfma_f32_16x16x32_bf16(
                        a[mh], b[n], acc[mh][n], 0, 0, 0);
        }
        #pragma unroll
        for (int mh = 0; mh < 2; ++mh) {
            const int c0 = (mg * 2 + mh) * 16 + lq * 4;
            #pragma unroll
            for (int n = 0; n < 4; ++n) {
                us4 pk;
                #pragma unroll
                for (int j = 0; j < 4; ++j) pk[j] = f2bf(acc[mh][n][j]);
                *(us4*)&CtP[(n * 16 + lr) * CT_ROW + c0] = pk;   // ds_write_b64
            }
        }
    }

    // ---- CONV: Y[o][t] = sum_{i,w} Wt[w][o][i]*Ct[t+w][i] ----
    f32x4 acc2[4][4];
    #pragma unroll
    for (int n = 0; n < 4; ++n)
        #pragma unroll
        for (int m = 0; m < 4; ++m) acc2[n][m] = (f32x4){0.f, 0.f, 0.f, 0.f};

    #pragma unroll 2
    for (int kc = 0; kc < 6; ++kc) {
        const int w  = kc >> 1;
        const int i0 = (kc & 1) * 32 + 8 * lq;
        short8b a[4], b[4];
        #pragma unroll
        for (int n = 0; n < 4; ++n)
            a[n] = *(const short8b*)&CtP[(n * 16 + lr + w) * CT_ROW + i0];
        #pragma unroll
        for (int m = 0; m < 4; ++m)
            b[m] = *(const short8b*)&Wt[(w * 64 + m * 16 + lr) * 64 + i0];
        #pragma unroll
        for (int n = 0; n < 4; ++n)
            #pragma unroll
            for (int m = 0; m < 4; ++m)
                acc2[n][m] = __builtin_amdgcn_mfma_f32_16x16x32_bf16(
                    a[n], b[m], acc2[n][m], 0, 0, 0);
    }
    // Y store (in place over own sample region; all conv A-reads already issued)
    #pragma unroll
    for (int n = 0; n < 4; ++n) {
        const int t0 = n * 16 + 4 * lq;
        #pragma unroll
        for (int m = 0; m < 4; ++m) {
            const int o = m * 16 + lr;
            us4 pk;
            #pragma unroll
            for (int j = 0; j < 4; ++j) pk[j] = f2bf(acc2[n][m][j] + bias[m]);
            *(us4*)&CtP[o * CT_ROW + t0] = pk;
        }
    }

    // ---- GEMM3: out[s][c=o] = sum_t U[s][t]*Y[o][t], split into s-halves ----
    #pragma unroll
    for (int mg = 0; mg < 2; ++mg) {
        f32x4 acc[2][4];
        #pragma unroll
        for (int i = 0; i < 2; ++i)
            #pragma unroll
            for (int ct = 0; ct < 4; ++ct) acc[i][ct] = (f32x4){0.f, 0.f, 0.f, 0.f};

        #pragma unroll
        for (int kc = 0; kc < 2; ++kc) {
            short8b a[2], b[4];
            #pragma unroll
            for (int mh = 0; mh < 2; ++mh)
                a[mh] = *(const short8b*)&Urm[((mg * 2 + mh) * 16 + lr) * 64 + kc * 32 + lq * 8];
            #pragma unroll
            for (int ct = 0; ct < 4; ++ct)
                b[ct] = *(const short8b*)&CtP[(ct * 16 + lr) * CT_ROW + kc * 32 + lq * 8];
            #pragma unroll
            for (int mh = 0; mh < 2; ++mh)
                #pragma unroll
                for (int ct = 0; ct < 4; ++ct)
                    acc[mh][ct] = __builtin_amdgcn_mfma_f32_16x16x32_bf16(
                        a[mh], b[ct], acc[mh][ct], 0, 0, 0);
        }
        #pragma unroll
        for (int mh = 0; mh < 2; ++mh) {
            const int s0 = (mg * 2 + mh) * 16 + lq * 4;
            const int n  = s0 >> 3;
            const int m0 = s0 & 7;
            #pragma unroll
            for (int ct = 0; ct < 4; ++ct) {
                const int o = ct * 16 + lr;
                float4 st = make_float4(acc[mh][ct][0], acc[mh][ct][1],
                                        acc[mh][ct][2], acc[mh][ct][3]);
                *(float4*)(out + (((size_t)bz * CH + o) * HW + by * 8 + n) * HW
                           + bxs * 8 + m0) = st;
            }
        }
    }
}

extern "C" void kernel_launch(void* const* d_in, const int* in_sizes, int n_in,
                              void* d_out, int out_size, void* d_ws, size_t ws_size,
                              hipStream_t stream) {
    const float* x  = (const float*)d_in[0];
    const float* cw = (const float*)d_in[1];
    const float* cb = (const float*)d_in[2];
    float* o        = (float*)d_out;
    unsigned short* ws16 = (unsigned short*)d_ws;    // 40960 B used

    prep_kernel<<<dim3(80), dim3(256), 0, stream>>>(cw, ws16);

    hipFuncSetAttribute(reinterpret_cast<const void*>(dct_freq_conv_kernel),
                        hipFuncAttributeMaxDynamicSharedMemorySize,
                        (int)LDS_BYTES);
    dim3 grid(8, 32, 8);  // (bx/4, by, bz) = 2048 WGs
    dct_freq_conv_kernel<<<grid, dim3(THREADS), LDS_BYTES, stream>>>(x, ws16, cb, o);
}

// Round 5
// 258.385 us; speedup vs baseline: 1.1068x; 1.1068x over previous
//
#include <hip/hip_runtime.h>

// DCTFreqConv, all-MFMA per-wave pipeline, transaction-coalesced.
// Per sample: GEMM1 Ct[t][c]=sum_s X[c][s]T[t][s]; CONV Y[o][t]=sum_{i,w}W[o,i,w]Ct[t+w][i]+b;
// GEMM3 out[s][c]=sum_t U[s][t]Y[o=c][t].  Wave = 1 sample, 4/WG.
// All global traffic coalesced: x staged via LDS (bf16, XOR-swizzled, 2 K-halves);
// T/U/Wt pre-swizzled fragment-linear in d_ws (1KB dense wave-loads, L1-hit);
// out transposed through LDS (f32) in 4 quarter-tiles reusing the staging region.
// LDS = 16384 (Xb/Ou) + 38016 (Ct) = 54400 B -> 3 WG/CU.

#define THREADS 256
#define HW 256
#define CH 64
#define CT_ROW 72                    // shorts (144 B): 2-way-free banks for row reads
#define CT_SAMPLE (66 * CT_ROW)      // rows 64,65 zero pad for conv t+2 shift
#define XB_SH 8192                   // staging region: 4smp x 64c x 32k shorts = 16384 B
#define LDS_BYTES ((XB_SH + 4 * CT_SAMPLE) * 2)   // 54400

typedef __attribute__((ext_vector_type(8))) short short8b;
typedef __attribute__((ext_vector_type(4))) float f32x4;
typedef __attribute__((ext_vector_type(4))) unsigned short us4;

__device__ inline unsigned short f2bf(float f) {
    unsigned u = __builtin_bit_cast(unsigned, f);
    u += 0x7FFFu + ((u >> 16) & 1u);
    return (unsigned short)(u >> 16);
}

__device__ __constant__ static const float D8[8][8] = {
  { 0.3535533906f, 0.3535533906f, 0.3535533906f, 0.3535533906f, 0.3535533906f, 0.3535533906f, 0.3535533906f, 0.3535533906f },
  { 0.4903926402f, 0.4157348062f, 0.2777851165f, 0.0975451610f,-0.0975451610f,-0.2777851165f,-0.4157348062f,-0.4903926402f },
  { 0.4619397663f, 0.1913417162f,-0.1913417162f,-0.4619397663f,-0.4619397663f,-0.1913417162f, 0.1913417162f, 0.4619397663f },
  { 0.4157348062f,-0.0975451610f,-0.4903926402f,-0.2777851165f, 0.2777851165f, 0.4903926402f, 0.0975451610f,-0.4157348062f },
  { 0.3535533906f,-0.3535533906f,-0.3535533906f, 0.3535533906f, 0.3535533906f,-0.3535533906f,-0.3535533906f, 0.3535533906f },
  { 0.2777851165f,-0.4903926402f, 0.0975451610f, 0.4157348062f,-0.4157348062f,-0.0975451610f, 0.4903926402f,-0.2777851165f },
  { 0.1913417162f,-0.4619397663f, 0.4619397663f,-0.1913417162f,-0.1913417162f, 0.4619397663f,-0.4619397663f, 0.1913417162f },
  { 0.0975451610f,-0.2777851165f, 0.4157348062f,-0.4903926402f, 0.4903926402f,-0.4157348062f, 0.2777851165f,-0.0975451610f },
};

// d_ws shorts: [0,4096) Tf frag-linear; [4096,8192) Uf; [8192,20480) Wf.
// Fragment order: element j of lane `lane` of fragment f lives at (f*64+lane)*8+j.
__global__ __launch_bounds__(256)
void prep_kernel(const float* __restrict__ conv_w, unsigned short* __restrict__ ws16) {
    int idx = blockIdx.x * 256 + threadIdx.x;      // 20480 total
    int j = idx & 7, lane = (idx >> 3) & 63;
    int lrr = lane & 15, lqq = lane >> 4;
    if (idx < 4096) {                              // Tf: frag (n,kc): B[t=n*16+lr][s]
        int nk = idx >> 9, n = nk >> 1, kc = nk & 1;
        int t = n * 16 + lrr, s = kc * 32 + lqq * 8 + j;
        ws16[idx] = f2bf(D8[t >> 3][s >> 3] * D8[t & 7][s & 7]);
    } else if (idx < 8192) {                       // Uf: frag (m,kc): A[s=m*16+lr][t]
        int i2 = idx - 4096;
        int mk = i2 >> 9, m = mk >> 1, kc = mk & 1;
        int s = m * 16 + lrr, t = kc * 32 + lqq * 8 + j;
        ws16[idx] = f2bf(D8[t >> 3][s >> 3] * D8[t & 7][s & 7]);
    } else if (idx < 20480) {                      // Wf: frag (w,hc,m): B[o=m*16+lr][i]
        int i3 = idx - 8192;
        int grp = i3 >> 9, m = grp & 3, hc = (grp >> 2) & 1, w = grp >> 3;
        int o = m * 16 + lrr, i = hc * 32 + lqq * 8 + j;
        ws16[idx] = f2bf(conv_w[o * 192 + i * 3 + w]);
    }
}

__global__ __launch_bounds__(THREADS, 3)
void dct_freq_conv_kernel(const float* __restrict__ x,
                          const unsigned short* __restrict__ ws16,
                          const float* __restrict__ conv_b,
                          float* __restrict__ out)
{
    extern __shared__ char smem[];
    unsigned short* Xb = (unsigned short*)smem;            // [4smp][64c][32k] swizzled
    float*          Ou = (float*)smem;                     // same bytes, f32 out-tile
    unsigned short* Ct = (unsigned short*)smem + XB_SH;    // [4smp][66][72]
    const unsigned short* Tf = ws16;
    const unsigned short* Uf = ws16 + 4096;
    const unsigned short* Wf = ws16 + 8192;

    const int tid = threadIdx.x;
    const int wid = tid >> 6, lane = tid & 63;
    const int lr = lane & 15, lq = lane >> 4;
    const int bz = blockIdx.z, by = blockIdx.y, bx = blockIdx.x;
    unsigned short* CtP = Ct + wid * CT_SAMPLE;

    // zero pad rows t=64,65 of own sample (wave-local, lgkm-ordered vs conv reads)
    if (lane < 36) *(us4*)&CtP[64 * CT_ROW + lane * 4] = (us4){0, 0, 0, 0};

    float bias[4];
    #pragma unroll
    for (int m = 0; m < 4; ++m) bias[m] = conv_b[m * 16 + lr];

    // ---- coalesced x staging: half h = spatial rows [h*4, h*4+4) ----
    auto stage = [&](int h) {
        #pragma unroll
        for (int rep = 0; rep < 8; ++rep) {
            int f4 = rep * 256 + tid;                     // 2048 float4 per half
            int cl = f4 & 7, rl = (f4 >> 3) & 3, c = f4 >> 5;
            const float* gp = x + ((size_t)(bz * 64 + c) * 256 + by * 8 + h * 4 + rl) * 256
                                + bx * 32 + cl * 4;
            float4 v = *(const float4*)gp;
            us4 pk; pk[0] = f2bf(v.x); pk[1] = f2bf(v.y); pk[2] = f2bf(v.z); pk[3] = f2bf(v.w);
            int smp = cl >> 1, kk = rl * 8 + (cl & 1) * 4;
            *(us4*)&Xb[smp * 2048 + c * 32 + (kk ^ ((c & 3) << 3))] = pk;
        }
    };

    // ---- GEMM1: Ct[t][c] = sum_s X[c][s] * T[t][s] ----
    f32x4 acc[4][4];
    #pragma unroll
    for (int m = 0; m < 4; ++m)
        #pragma unroll
        for (int n = 0; n < 4; ++n) acc[m][n] = (f32x4){0.f, 0.f, 0.f, 0.f};

    auto gemm1_step = [&](int kc) {
        short8b a[4], b[4];
        #pragma unroll
        for (int m = 0; m < 4; ++m) {
            const int cA = m * 16 + lr;
            a[m] = *(const short8b*)&Xb[wid * 2048 + cA * 32 + ((lq * 8) ^ ((cA & 3) << 3))];
        }
        #pragma unroll
        for (int n = 0; n < 4; ++n)
            b[n] = *(const short8b*)&Tf[((n * 2 + kc) * 64 + lane) * 8];
        #pragma unroll
        for (int m = 0; m < 4; ++m)
            #pragma unroll
            for (int n = 0; n < 4; ++n)
                acc[m][n] = __builtin_amdgcn_mfma_f32_16x16x32_bf16(a[m], b[n], acc[m][n], 0, 0, 0);
    };

    stage(0);
    __syncthreads();
    gemm1_step(0);
    __syncthreads();          // protect Xb rewrite
    stage(1);
    __syncthreads();
    gemm1_step(1);

    // Ct write: D row = c = m*16+lq*4+reg, col = t = n*16+lr
    #pragma unroll
    for (int m = 0; m < 4; ++m)
        #pragma unroll
        for (int n = 0; n < 4; ++n) {
            us4 pk;
            #pragma unroll
            for (int j = 0; j < 4; ++j) pk[j] = f2bf(acc[m][n][j]);
            *(us4*)&CtP[(n * 16 + lr) * CT_ROW + m * 16 + lq * 4] = pk;
        }

    // ---- CONV: Y[o][t] = sum_{i,w} W[o,i,w] * Ct[t+w][i]  (wave-local) ----
    f32x4 acc2[4][4];
    #pragma unroll
    for (int n = 0; n < 4; ++n)
        #pragma unroll
        for (int m = 0; m < 4; ++m) acc2[n][m] = (f32x4){0.f, 0.f, 0.f, 0.f};

    #pragma unroll
    for (int kc = 0; kc < 6; ++kc) {
        const int w  = kc >> 1;
        const int i0 = (kc & 1) * 32 + lq * 8;
        short8b a[4], b[4];
        #pragma unroll
        for (int n = 0; n < 4; ++n)
            a[n] = *(const short8b*)&CtP[(n * 16 + lr + w) * CT_ROW + i0];
        #pragma unroll
        for (int m = 0; m < 4; ++m)
            b[m] = *(const short8b*)&Wf[((kc * 4 + m) * 64 + lane) * 8];
        #pragma unroll
        for (int n = 0; n < 4; ++n)
            #pragma unroll
            for (int m = 0; m < 4; ++m)
                acc2[n][m] = __builtin_amdgcn_mfma_f32_16x16x32_bf16(a[n], b[m], acc2[n][m], 0, 0, 0);
    }
    // Y store: row = t = n*16+lq*4+reg, col = o = m*16+lr
    #pragma unroll
    for (int n = 0; n < 4; ++n)
        #pragma unroll
        for (int m = 0; m < 4; ++m) {
            us4 pk;
            #pragma unroll
            for (int j = 0; j < 4; ++j) pk[j] = f2bf(acc2[n][m][j] + bias[m]);
            *(us4*)&CtP[(m * 16 + lr) * CT_ROW + n * 16 + lq * 4] = pk;
        }

    // ---- GEMM3: out[s][c=o] = sum_t U[s][t] * Y[o][t], 4 quarter-tiles ----
    #pragma unroll
    for (int mg = 0; mg < 2; ++mg) {
        f32x4 a3[2][4];
        #pragma unroll
        for (int mh = 0; mh < 2; ++mh)
            #pragma unroll
            for (int ct = 0; ct < 4; ++ct) a3[mh][ct] = (f32x4){0.f, 0.f, 0.f, 0.f};

        #pragma unroll
        for (int kc = 0; kc < 2; ++kc) {
            short8b ua[2], yb[4];
            #pragma unroll
            for (int mh = 0; mh < 2; ++mh)
                ua[mh] = *(const short8b*)&Uf[(((mg * 2 + mh) * 2 + kc) * 64 + lane) * 8];
            #pragma unroll
            for (int ct = 0; ct < 4; ++ct)
                yb[ct] = *(const short8b*)&CtP[(ct * 16 + lr) * CT_ROW + kc * 32 + lq * 8];
            #pragma unroll
            for (int mh = 0; mh < 2; ++mh)
                #pragma unroll
                for (int ct = 0; ct < 4; ++ct)
                    a3[mh][ct] = __builtin_amdgcn_mfma_f32_16x16x32_bf16(ua[mh], yb[ct], a3[mh][ct], 0, 0, 0);
        }

        #pragma unroll
        for (int mh = 0; mh < 2; ++mh) {
            const int q = mg * 2 + mh;               // quarter: s in [q*16, q*16+16)
            // D row = s = q*16+lq*4+reg, col = o = ct*16+lr -> Ou[smp=wid][c=o][s_local]
            #pragma unroll
            for (int ct = 0; ct < 4; ++ct)
                *(f32x4*)&Ou[wid * 1024 + (ct * 16 + lr) * 16 + ((lq ^ wid) & 3) * 4] = a3[mh][ct];
            __syncthreads();
            // coalesced out store: per (c, row r), 8 lanes cover 128B
            #pragma unroll
            for (int rep = 0; rep < 4; ++rep) {
                int gl = tid & 1, smp = (tid >> 1) & 3, c = (rep & 1) * 32 + (tid >> 3);
                int gh = rep >> 1, g = gh * 2 + gl;
                f32x4 v = *(const f32x4*)&Ou[smp * 1024 + c * 16 + ((g ^ smp) & 3) * 4];
                int r = q * 2 + gh;
                *(float4*)(out + ((size_t)(bz * 64 + c) * 256 + by * 8 + r) * 256
                           + bx * 32 + smp * 8 + gl * 4)
                    = make_float4(v[0], v[1], v[2], v[3]);
            }
            __syncthreads();                          // protect Ou rewrite
        }
    }
}

extern "C" void kernel_launch(void* const* d_in, const int* in_sizes, int n_in,
                              void* d_out, int out_size, void* d_ws, size_t ws_size,
                              hipStream_t stream) {
    const float* x  = (const float*)d_in[0];
    const float* cw = (const float*)d_in[1];
    const float* cb = (const float*)d_in[2];
    float* o        = (float*)d_out;
    unsigned short* ws16 = (unsigned short*)d_ws;    // 40960 B used

    prep_kernel<<<dim3(80), dim3(256), 0, stream>>>(cw, ws16);

    hipFuncSetAttribute(reinterpret_cast<const void*>(dct_freq_conv_kernel),
                        hipFuncAttributeMaxDynamicSharedMemorySize,
                        (int)LDS_BYTES);
    dim3 grid(8, 32, 8);  // (bx, by, bz) = 2048 WGs, 4 samples each
    dct_freq_conv_kernel<<<grid, dim3(THREADS), LDS_BYTES, stream>>>(x, ws16, cb, o);
}

// Round 6
// 251.616 us; speedup vs baseline: 1.1366x; 1.0269x over previous
//
#include <hip/hip_runtime.h>

// DCTFreqConv, all-MFMA per-wave pipeline, conflict-free LDS + reduced barriers.
// Per sample: GEMM1 Ct[t][c]=sum_s X[c][s]T[t][s]; CONV Y[o][t]=sum_{i,w}W[o,i,w]Ct[t+w][i]+b;
// GEMM3 out[s][o]=sum_t U[s][t]Y[o][t].  Wave = 1 sample, 4 samples/WG.
// LDS: Xb 16384 B (staged x, bf16, swizzled) + Ct 4x8448 B ([66][64] shorts,
// XOR-16 row swizzle) = 50176 B -> 3 WG/CU. Output transposed through first
// 32 KB (reused) in 2 halves. T/U/W fragment-linear bf16 in d_ws (L1/L2-hit).

#define THREADS 256
#define XB_BYTES 16384
#define CT_STRIDE_B 8448                 // 66 rows * 128 B
#define LDS_BYTES (XB_BYTES + 4 * CT_STRIDE_B)   // 50176

typedef __attribute__((ext_vector_type(8))) short short8b;
typedef __attribute__((ext_vector_type(4))) float f32x4;
typedef __attribute__((ext_vector_type(4))) unsigned short us4;

__device__ inline unsigned short f2bf(float f) {
    unsigned u = __builtin_bit_cast(unsigned, f);
    u += 0x7FFFu + ((u >> 16) & 1u);
    return (unsigned short)(u >> 16);
}

__device__ __constant__ static const float D8[8][8] = {
  { 0.3535533906f, 0.3535533906f, 0.3535533906f, 0.3535533906f, 0.3535533906f, 0.3535533906f, 0.3535533906f, 0.3535533906f },
  { 0.4903926402f, 0.4157348062f, 0.2777851165f, 0.0975451610f,-0.0975451610f,-0.2777851165f,-0.4157348062f,-0.4903926402f },
  { 0.4619397663f, 0.1913417162f,-0.1913417162f,-0.4619397663f,-0.4619397663f,-0.1913417162f, 0.1913417162f, 0.4619397663f },
  { 0.4157348062f,-0.0975451610f,-0.4903926402f,-0.2777851165f, 0.2777851165f, 0.4903926402f, 0.0975451610f,-0.4157348062f },
  { 0.3535533906f,-0.3535533906f,-0.3535533906f, 0.3535533906f, 0.3535533906f,-0.3535533906f,-0.3535533906f, 0.3535533906f },
  { 0.2777851165f,-0.4903926402f, 0.0975451610f, 0.4157348062f,-0.4157348062f,-0.0975451610f, 0.4903926402f,-0.2777851165f },
  { 0.1913417162f,-0.4619397663f, 0.4619397663f,-0.1913417162f,-0.1913417162f, 0.4619397663f,-0.4619397663f, 0.1913417162f },
  { 0.0975451610f,-0.2777851165f, 0.4157348062f,-0.4903926402f, 0.4903926402f,-0.4157348062f, 0.2777851165f,-0.0975451610f },
};

// d_ws shorts: [0,4096) Tf frag-linear; [4096,8192) Uf; [8192,20480) Wf.
// Element j of lane `lane` of fragment f at (f*64+lane)*8+j.
__global__ __launch_bounds__(256)
void prep_kernel(const float* __restrict__ conv_w, unsigned short* __restrict__ ws16) {
    int idx = blockIdx.x * 256 + threadIdx.x;      // 20480 total
    int j = idx & 7, lane = (idx >> 3) & 63;
    int lrr = lane & 15, lqq = lane >> 4;
    if (idx < 4096) {                              // Tf frag (n,h): B[t=n*16+lr][s]
        int nk = idx >> 9, n = nk >> 1, h = nk & 1;
        int t = n * 16 + lrr, s = h * 32 + lqq * 8 + j;
        ws16[idx] = f2bf(D8[t >> 3][s >> 3] * D8[t & 7][s & 7]);
    } else if (idx < 8192) {                       // Uf frag (m,kc): A[s=m*16+lr][t]
        int i2 = idx - 4096;
        int mk = i2 >> 9, m = mk >> 1, kc = mk & 1;
        int s = m * 16 + lrr, t = kc * 32 + lqq * 8 + j;
        ws16[idx] = f2bf(D8[t >> 3][s >> 3] * D8[t & 7][s & 7]);
    } else if (idx < 20480) {                      // Wf frag (w,hc,m): B[o=m*16+lr][i]
        int i3 = idx - 8192;
        int grp = i3 >> 9, m = grp & 3, hc = (grp >> 2) & 1, w = grp >> 3;
        int o = m * 16 + lrr, i = hc * 32 + lqq * 8 + j;
        ws16[idx] = f2bf(conv_w[o * 192 + i * 3 + w]);
    }
}

__global__ __launch_bounds__(THREADS, 3)
void dct_freq_conv_kernel(const float* __restrict__ x,
                          const unsigned short* __restrict__ ws16,
                          const float* __restrict__ conv_b,
                          float* __restrict__ out)
{
    extern __shared__ char smem[];
    char* XbB = smem;                         // [4smp][64c][4 slots of 16B], swizzled
    char* CtB = smem + XB_BYTES;              // [4smp][66 rows][128 B], XOR-16 swizzled
    const unsigned short* Tf = ws16;
    const unsigned short* Uf = ws16 + 4096;
    const unsigned short* Wf = ws16 + 8192;

    const int tid = threadIdx.x;
    const int wid = tid >> 6, lane = tid & 63;
    const int lr = lane & 15, lq = lane >> 4;
    const int bz = blockIdx.z, by = blockIdx.y, bx = blockIdx.x;
    char* CtP = CtB + wid * CT_STRIDE_B;

    // zero pad rows t=64,65 of own sample (wave-local; consumed after data deps)
    if (lane < 32) {
        int rp = lane >> 4, cq = lane & 15;
        int byte = (64 + rp) * 128 + (((cq >> 1) ^ rp) << 4) + (cq & 1) * 8;
        *(us4*)(CtP + byte) = (us4){0, 0, 0, 0};
    }

    float bias[4];
    #pragma unroll
    for (int m = 0; m < 4; ++m) bias[m] = conv_b[m * 16 + lr];

    // ---- x staging helpers (half h = spatial rows [h*4, h*4+4)) ----
    auto stage_load = [&](int h, int rep) -> float4 {
        int f4 = rep * 256 + tid;
        int cl = f4 & 7, rl = (f4 >> 3) & 3, c = f4 >> 5;
        return *(const float4*)(x + ((size_t)(bz * 64 + c) * 256 + by * 8 + h * 4 + rl) * 256
                                + bx * 32 + cl * 4);
    };
    auto stage_store = [&](int rep, float4 v) {
        int f4 = rep * 256 + tid;
        int cl = f4 & 7, rl = (f4 >> 3) & 3, c = f4 >> 5;
        int smp = cl >> 1;
        us4 pk; pk[0] = f2bf(v.x); pk[1] = f2bf(v.y); pk[2] = f2bf(v.z); pk[3] = f2bf(v.w);
        *(us4*)(XbB + smp * 4096 + c * 64 + ((rl ^ smp ^ ((c >> 1) & 3)) << 4)
                + (cl & 1) * 8) = pk;
    };

    // ---- GEMM1: Ct[t][c] = sum_s X[c][s] * T[t][s] ----
    f32x4 acc1[4][4];
    #pragma unroll
    for (int m = 0; m < 4; ++m)
        #pragma unroll
        for (int n = 0; n < 4; ++n) acc1[m][n] = (f32x4){0.f, 0.f, 0.f, 0.f};

    auto gemm1_step = [&](int h) {
        short8b a[4], b[4];
        #pragma unroll
        for (int m = 0; m < 4; ++m) {
            const int c = m * 16 + lr;
            a[m] = *(const short8b*)(XbB + wid * 4096 + c * 64
                                     + ((lq ^ wid ^ ((lr >> 1) & 3)) << 4));
        }
        #pragma unroll
        for (int n = 0; n < 4; ++n)
            b[n] = *(const short8b*)&Tf[((n * 2 + h) * 64 + lane) * 8];
        #pragma unroll
        for (int m = 0; m < 4; ++m)
            #pragma unroll
            for (int n = 0; n < 4; ++n)
                acc1[m][n] = __builtin_amdgcn_mfma_f32_16x16x32_bf16(a[m], b[n], acc1[m][n], 0, 0, 0);
    };

    #pragma unroll
    for (int rep = 0; rep < 8; ++rep) stage_store(rep, stage_load(0, rep));
    __syncthreads();                                   // BAR1
    float4 xr[8];                                      // T14: issue h1 loads early
    #pragma unroll
    for (int rep = 0; rep < 8; ++rep) xr[rep] = stage_load(1, rep);
    gemm1_step(0);
    __syncthreads();                                   // BAR2 (Xb reads done)
    #pragma unroll
    for (int rep = 0; rep < 8; ++rep) stage_store(rep, xr[rep]);
    __syncthreads();                                   // BAR3
    gemm1_step(1);

    // Ct write: D -> row t = n*16+lr, col c = m*16+lq*4 (+j), swizzled
    #pragma unroll
    for (int m = 0; m < 4; ++m)
        #pragma unroll
        for (int n = 0; n < 4; ++n) {
            int row = n * 16 + lr;
            int byte = row * 128 + (((m * 2 + (lq >> 1)) ^ (lr & 7)) << 4) + (lq & 1) * 8;
            us4 pk;
            #pragma unroll
            for (int j = 0; j < 4; ++j) pk[j] = f2bf(acc1[m][n][j]);
            *(us4*)(CtP + byte) = pk;
        }

    // ---- CONV: Y[o][t] = sum_{i,w} W[o,i,w] * Ct[t+w][i]  (wave-local) ----
    f32x4 acc2[4][4];
    #pragma unroll
    for (int n = 0; n < 4; ++n)
        #pragma unroll
        for (int m = 0; m < 4; ++m) acc2[n][m] = (f32x4){0.f, 0.f, 0.f, 0.f};

    #pragma unroll
    for (int kc = 0; kc < 6; ++kc) {
        const int w = kc >> 1;
        short8b a[4], b[4];
        #pragma unroll
        for (int n = 0; n < 4; ++n) {
            int row = n * 16 + lr + w;
            int slot = (kc & 1) * 4 + lq;
            a[n] = *(const short8b*)(CtP + row * 128 + ((slot ^ (row & 7)) << 4));
        }
        #pragma unroll
        for (int m = 0; m < 4; ++m)
            b[m] = *(const short8b*)&Wf[((kc * 4 + m) * 64 + lane) * 8];
        #pragma unroll
        for (int n = 0; n < 4; ++n)
            #pragma unroll
            for (int m = 0; m < 4; ++m)
                acc2[n][m] = __builtin_amdgcn_mfma_f32_16x16x32_bf16(a[n], b[m], acc2[n][m], 0, 0, 0);
    }
    // Y write: row o = m*16+lr, col t = n*16+lq*4 (+j)  (safe via data deps)
    #pragma unroll
    for (int n = 0; n < 4; ++n)
        #pragma unroll
        for (int m = 0; m < 4; ++m) {
            int byte = (m * 16 + lr) * 128 + (((n * 2 + (lq >> 1)) ^ (lr & 7)) << 4) + (lq & 1) * 8;
            us4 pk;
            #pragma unroll
            for (int j = 0; j < 4; ++j) pk[j] = f2bf(acc2[n][m][j] + bias[m]);
            *(us4*)(CtP + byte) = pk;
        }

    // ---- GEMM3: out[s][o] = sum_t U[s][t] * Y[o][t], full 64 acc regs ----
    f32x4 acc3[4][4];                                  // [m4 = s-tile][ct = o-tile]
    #pragma unroll
    for (int m4 = 0; m4 < 4; ++m4)
        #pragma unroll
        for (int ct = 0; ct < 4; ++ct) acc3[m4][ct] = (f32x4){0.f, 0.f, 0.f, 0.f};

    #pragma unroll
    for (int kc = 0; kc < 2; ++kc) {
        short8b ua[4], yb[4];
        #pragma unroll
        for (int m4 = 0; m4 < 4; ++m4)
            ua[m4] = *(const short8b*)&Uf[((m4 * 2 + kc) * 64 + lane) * 8];
        #pragma unroll
        for (int ct = 0; ct < 4; ++ct) {
            int row = ct * 16 + lr;
            int slot = kc * 4 + lq;
            yb[ct] = *(const short8b*)(CtP + row * 128 + ((slot ^ (row & 7)) << 4));
        }
        #pragma unroll
        for (int m4 = 0; m4 < 4; ++m4)
            #pragma unroll
            for (int ct = 0; ct < 4; ++ct)
                acc3[m4][ct] = __builtin_amdgcn_mfma_f32_16x16x32_bf16(ua[m4], yb[ct], acc3[m4][ct], 0, 0, 0);
    }

    // ---- Output: 2 halves through Ou (first 32 KB, swizzled), coalesced ----
    __syncthreads();                                   // BAR4: all Ct reads done
    char* OuP = smem + wid * 8192;                     // per-wave 8 KB: [o][32 s_half floats]
    #pragma unroll
    for (int hh = 0; hh < 2; ++hh) {
        #pragma unroll
        for (int mh = 0; mh < 2; ++mh)
            #pragma unroll
            for (int ct = 0; ct < 4; ++ct) {
                int o = ct * 16 + lr;
                int slot = mh * 4 + lq;                // s_half = mh*16+lq*4
                *(f32x4*)(OuP + o * 128 + ((slot ^ (o & 7)) << 4)) = acc3[hh * 2 + mh][ct];
            }
        __syncthreads();                               // BAR5 / BAR7
        #pragma unroll
        for (int rep = 0; rep < 8; ++rep) {
            int f4 = rep * 256 + tid;
            int gl = f4 & 7, c = (f4 >> 3) & 63, rr = f4 >> 9;
            int smp = gl >> 1;
            int slot = rr * 2 + (gl & 1);              // s_half = rr*8+(gl&1)*4
            f32x4 v = *(const f32x4*)(smem + smp * 8192 + c * 128 + ((slot ^ (c & 7)) << 4));
            *(float4*)(out + ((size_t)(bz * 64 + c) * 256 + by * 8 + hh * 4 + rr) * 256
                       + bx * 32 + gl * 4) = make_float4(v[0], v[1], v[2], v[3]);
        }
        if (hh == 0) __syncthreads();                  // BAR6: before half-1 overwrite
    }
}

extern "C" void kernel_launch(void* const* d_in, const int* in_sizes, int n_in,
                              void* d_out, int out_size, void* d_ws, size_t ws_size,
                              hipStream_t stream) {
    const float* x  = (const float*)d_in[0];
    const float* cw = (const float*)d_in[1];
    const float* cb = (const float*)d_in[2];
    float* o        = (float*)d_out;
    unsigned short* ws16 = (unsigned short*)d_ws;      // 40960 B used

    prep_kernel<<<dim3(80), dim3(256), 0, stream>>>(cw, ws16);

    hipFuncSetAttribute(reinterpret_cast<const void*>(dct_freq_conv_kernel),
                        hipFuncAttributeMaxDynamicSharedMemorySize,
                        (int)LDS_BYTES);
    dim3 grid(8, 32, 8);  // 2048 WGs, 4 samples each
    dct_freq_conv_kernel<<<grid, dim3(THREADS), LDS_BYTES, stream>>>(x, ws16, cb, o);
}